// Round 1
// baseline (397.114 us; speedup 1.0000x reference)
//
#include <hip/hip_runtime.h>
#include <hip/hip_bf16.h>

// B=4 T=2048 C=1024 H=16 hd=64, causal MHSA, f32 in/out, bf16 MFMA internally.
// Pipeline: cvt(x) / transpose-cvt(w) -> GEMM1 (qkv) -> transpose V -> flash attn -> GEMM2.

typedef float __attribute__((ext_vector_type(4))) f32x4;
typedef __bf16 __attribute__((ext_vector_type(8))) bf16x8;
typedef short __attribute__((ext_vector_type(8))) short8v;

__device__ __forceinline__ unsigned short f2bf(float f) {
  __hip_bfloat16 h = __float2bfloat16(f);
  return __builtin_bit_cast(unsigned short, h);
}

__device__ __forceinline__ void glds16(const void* g, void* l) {
  __builtin_amdgcn_global_load_lds((const __attribute__((address_space(1))) void*)g,
                                   (__attribute__((address_space(3))) void*)l, 16, 0, 0);
}

// ---------------- conversions ----------------
__global__ void cvt_f32_bf16_kernel(const float* __restrict__ in,
                                    unsigned short* __restrict__ out, int n) {
  int stride = gridDim.x * blockDim.x * 4;
  for (int i = (blockIdx.x * blockDim.x + threadIdx.x) * 4; i < n; i += stride) {
    float4 v = *(const float4*)(in + i);
    ushort4 o;
    o.x = f2bf(v.x); o.y = f2bf(v.y); o.z = f2bf(v.z); o.w = f2bf(v.w);
    *(ushort4*)(out + i) = o;
  }
}

// in: [K][N] f32 row-major -> out: [N][K] bf16 row-major
__global__ void transpose_cvt_kernel(const float* __restrict__ in,
                                     unsigned short* __restrict__ out, int K, int N) {
  __shared__ unsigned short tile[32][33];
  int tx = threadIdx.x & 31, ty = threadIdx.x >> 5;
  int n0 = blockIdx.x * 32, k0 = blockIdx.y * 32;
#pragma unroll
  for (int i = 0; i < 32; i += 8)
    tile[ty + i][tx] = f2bf(in[(size_t)(k0 + ty + i) * N + n0 + tx]);
  __syncthreads();
#pragma unroll
  for (int i = 0; i < 32; i += 8)
    out[(size_t)(n0 + ty + i) * K + k0 + tx] = tile[tx][ty + i];
}

// ---------------- GEMM: C[m][n] = sum_k A[m][k]*Bt[n][k] + bias[n] ----------------
// 128x128 tile, BK=32, 4 waves (2x2), 4x4 16x16x32 frags/wave. m97-style.
template <int OUT_F32>
__global__ __launch_bounds__(256) void gemm_bt_kernel(
    const unsigned short* __restrict__ A, const unsigned short* __restrict__ Bt,
    const float* __restrict__ bias, void* __restrict__ Cv, int M, int N, int K) {
  __shared__ unsigned short sA[128 * 32];
  __shared__ unsigned short sB[128 * 32];
  int tid = threadIdx.x;
  int lane = tid & 63, wid = tid >> 6;
  int g = lane >> 4, r16 = lane & 15;
  int m0 = blockIdx.y * 128, n0 = blockIdx.x * 128;
  int wm = wid >> 1, wn = wid & 1;
  f32x4 acc[4][4] = {};
  int srow = tid >> 2, scol = (tid & 3) * 8;
  const unsigned short* Ap0 = A + (size_t)(m0 + srow) * K + scol;
  const unsigned short* Ap1 = A + (size_t)(m0 + 64 + srow) * K + scol;
  const unsigned short* Bp0 = Bt + (size_t)(n0 + srow) * K + scol;
  const unsigned short* Bp1 = Bt + (size_t)(n0 + 64 + srow) * K + scol;
  unsigned short* la0 = sA + tid * 8;
  unsigned short* la1 = sA + 2048 + tid * 8;
  unsigned short* lb0 = sB + tid * 8;
  unsigned short* lb1 = sB + 2048 + tid * 8;
  for (int kt = 0; kt < K; kt += 32) {
    glds16(Ap0 + kt, la0);
    glds16(Ap1 + kt, la1);
    glds16(Bp0 + kt, lb0);
    glds16(Bp1 + kt, lb1);
    __syncthreads();
    bf16x8 af[4], bfr[4];
#pragma unroll
    for (int m = 0; m < 4; ++m)
      af[m] = *(const bf16x8*)&sA[(wm * 64 + m * 16 + r16) * 32 + g * 8];
#pragma unroll
    for (int n = 0; n < 4; ++n)
      bfr[n] = *(const bf16x8*)&sB[(wn * 64 + n * 16 + r16) * 32 + g * 8];
#pragma unroll
    for (int m = 0; m < 4; ++m)
#pragma unroll
      for (int n = 0; n < 4; ++n)
        acc[m][n] = __builtin_amdgcn_mfma_f32_16x16x32_bf16(af[m], bfr[n], acc[m][n], 0, 0, 0);
    __syncthreads();
  }
#pragma unroll
  for (int m = 0; m < 4; ++m)
#pragma unroll
    for (int n = 0; n < 4; ++n)
#pragma unroll
      for (int r = 0; r < 4; ++r) {
        int row = m0 + wm * 64 + m * 16 + g * 4 + r;
        int col = n0 + wn * 64 + n * 16 + r16;
        float v = acc[m][n][r] + bias[col];
        if (OUT_F32)
          ((float*)Cv)[(size_t)row * N + col] = v;
        else
          ((unsigned short*)Cv)[(size_t)row * N + col] = f2bf(v);
      }
}

// ---------------- V transpose: qkv[:, 2048+h*64+d] -> vT[(bh*64+d)][t] ----------------
__global__ void transpose_v_kernel(const unsigned short* __restrict__ qkv,
                                   unsigned short* __restrict__ vT) {
  __shared__ unsigned short tl[64][80];  // [d][t], padded stride 160B (16B-aligned)
  int t0 = blockIdx.x * 64;
  int bh = blockIdx.y, b = bh >> 4, h = bh & 15;
  int tid = threadIdx.x;
  int row = tid >> 2, c0 = (tid & 3) * 16;  // row = t-local, c0 = d start
  const unsigned short* src =
      qkv + (size_t)(b * 2048 + t0 + row) * 3072 + 2048 + h * 64 + c0;
  short8v a0 = *(const short8v*)src;
  short8v a1 = *(const short8v*)(src + 8);
#pragma unroll
  for (int j = 0; j < 8; ++j) tl[c0 + j][row] = (unsigned short)a0[j];
#pragma unroll
  for (int j = 0; j < 8; ++j) tl[c0 + 8 + j][row] = (unsigned short)a1[j];
  __syncthreads();
  int d = tid >> 2, tc = (tid & 3) * 16;
  unsigned short* dst = vT + (size_t)(bh * 64 + d) * 2048 + t0 + tc;
  *(short8v*)dst = *(const short8v*)&tl[d][tc];
  *(short8v*)(dst + 8) = *(const short8v*)&tl[d][tc + 8];
}

// ---------------- flash attention ----------------
// Block: 256 threads = 4 waves; 64 q-rows/block (16 per wave); KV tiles of 64.
// K/Vt/Q tiles staged by global_load_lds with pre-swizzled SOURCE; reads XOR-deswizzle
// (octet ^= row&7) so row-major [64][64] B-frag reads are bank-conflict-free.
__global__ __launch_bounds__(256) void attn_kernel(
    const unsigned short* __restrict__ qkv, const unsigned short* __restrict__ vT,
    unsigned short* __restrict__ ao) {
  __shared__ unsigned short sQ[64 * 64];
  __shared__ unsigned short sK[64 * 64];
  __shared__ unsigned short sV[64 * 64];      // V^T tile: [d][kv]
  __shared__ unsigned short sP[4][16 * 64];   // per-wave P, swizzled
  const int T = 2048, C3 = 3072;
  int qt = blockIdx.x, bh = blockIdx.y;
  int b = bh >> 4, h = bh & 15;
  int q0 = qt * 64;
  int tid = threadIdx.x, lane = tid & 63, w = tid >> 6;
  int g = lane >> 4, r16 = lane & 15;

  // stage Q (swizzled source)
#pragma unroll
  for (int i = 0; i < 2; ++i) {
    int c = i * 256 + tid;
    int row = c >> 3, oct = (c & 7) ^ (row & 7);
    glds16(qkv + (size_t)(b * T + q0 + row) * C3 + h * 64 + oct * 8, sQ + c * 8);
  }

  f32x4 oacc[4] = {};
  float m_r[4], l_r[4];
#pragma unroll
  for (int r = 0; r < 4; ++r) { m_r[r] = -1e30f; l_r[r] = 0.f; }

  __syncthreads();
  bf16x8 qf[2];
  int qrow = w * 16 + r16;
#pragma unroll
  for (int kk = 0; kk < 2; ++kk) {
    int oct = (kk * 4 + g) ^ (r16 & 7);
    qf[kk] = *(const bf16x8*)&sQ[qrow * 64 + oct * 8];
  }

  int nkv = qt + 1;
  for (int kt = 0; kt < nkv; ++kt) {
    int kv0 = kt * 64;
#pragma unroll
    for (int i = 0; i < 2; ++i) {
      int c = i * 256 + tid;
      int row = c >> 3, oct = (c & 7) ^ (row & 7);
      glds16(qkv + (size_t)(b * T + kv0 + row) * C3 + 1024 + h * 64 + oct * 8, sK + c * 8);
      glds16(vT + (size_t)(bh * 64 + row) * 2048 + kv0 + oct * 8, sV + c * 8);
    }
    __syncthreads();

    // S = Q K^T  (C-frag: q=(l>>4)*4+r, kv=n*16+(l&15))
    f32x4 s[4] = {};
#pragma unroll
    for (int kk = 0; kk < 2; ++kk) {
      int oct = (kk * 4 + g) ^ (r16 & 7);
#pragma unroll
      for (int n = 0; n < 4; ++n) {
        bf16x8 kf = *(const bf16x8*)&sK[(n * 16 + r16) * 64 + oct * 8];
        s[n] = __builtin_amdgcn_mfma_f32_16x16x32_bf16(qf[kk], kf, s[n], 0, 0, 0);
      }
    }

    // online softmax
    bool diag = (kt == qt);
    float rowmax[4] = {-1e30f, -1e30f, -1e30f, -1e30f};
    float sc[4][4];
#pragma unroll
    for (int n = 0; n < 4; ++n)
#pragma unroll
      for (int r = 0; r < 4; ++r) {
        float v = s[n][r] * 0.125f;
        if (diag && (n * 16 + r16) > (w * 16 + g * 4 + r)) v = -1e30f;
        sc[n][r] = v;
        rowmax[r] = fmaxf(rowmax[r], v);
      }
#pragma unroll
    for (int off = 1; off < 16; off <<= 1)
#pragma unroll
      for (int r = 0; r < 4; ++r)
        rowmax[r] = fmaxf(rowmax[r], __shfl_xor(rowmax[r], off, 64));
    float alpha[4], rowsum[4];
#pragma unroll
    for (int r = 0; r < 4; ++r) {
      float mn = fmaxf(m_r[r], rowmax[r]);
      alpha[r] = exp2f((m_r[r] - mn) * 1.44269504089f);
      m_r[r] = mn;
      rowsum[r] = 0.f;
    }
#pragma unroll
    for (int n = 0; n < 4; ++n)
#pragma unroll
      for (int r = 0; r < 4; ++r) {
        float p = exp2f((sc[n][r] - m_r[r]) * 1.44269504089f);
        rowsum[r] += p;
        int q = g * 4 + r, kv = n * 16 + r16;
        sP[w][q * 64 + (((kv >> 3) ^ (q & 7)) << 3) + (kv & 7)] = f2bf(p);
      }
#pragma unroll
    for (int off = 1; off < 16; off <<= 1)
#pragma unroll
      for (int r = 0; r < 4; ++r)
        rowsum[r] += __shfl_xor(rowsum[r], off, 64);
#pragma unroll
    for (int r = 0; r < 4; ++r) l_r[r] = l_r[r] * alpha[r] + rowsum[r];
#pragma unroll
    for (int n = 0; n < 4; ++n)
#pragma unroll
      for (int r = 0; r < 4; ++r) oacc[n][r] *= alpha[r];

    // O += P V   (A = P [16q x 64kv], B = V [kv x d] read from V^T rows)
#pragma unroll
    for (int kk = 0; kk < 2; ++kk) {
      int oct = (kk * 4 + g) ^ (r16 & 7);
      bf16x8 pf = *(const bf16x8*)&sP[w][r16 * 64 + oct * 8];
#pragma unroll
      for (int n2 = 0; n2 < 4; ++n2) {
        bf16x8 vf = *(const bf16x8*)&sV[(n2 * 16 + r16) * 64 + oct * 8];
        oacc[n2] = __builtin_amdgcn_mfma_f32_16x16x32_bf16(pf, vf, oacc[n2], 0, 0, 0);
      }
    }
    __syncthreads();
  }

#pragma unroll
  for (int r = 0; r < 4; ++r) l_r[r] = 1.f / l_r[r];
#pragma unroll
  for (int n2 = 0; n2 < 4; ++n2)
#pragma unroll
    for (int r = 0; r < 4; ++r) {
      int q = q0 + w * 16 + g * 4 + r;
      int d = h * 64 + n2 * 16 + r16;
      ao[(size_t)(b * T + q) * 1024 + d] = f2bf(oacc[n2][r] * l_r[r]);
    }
}

// ---------------- launch ----------------
extern "C" void kernel_launch(void* const* d_in, const int* in_sizes, int n_in,
                              void* d_out, int out_size, void* d_ws, size_t ws_size,
                              hipStream_t stream) {
  const float* x      = (const float*)d_in[0];
  const float* w_qkv  = (const float*)d_in[1];
  const float* b_qkv  = (const float*)d_in[2];
  const float* w_proj = (const float*)d_in[3];
  const float* b_proj = (const float*)d_in[4];
  float* out = (float*)d_out;

  char* ws = (char*)d_ws;
  // layout (bytes): xb/ao alias [0,16M), wqkvT [16M,22M), wprojT [22M,24M),
  // qkv [24M,72M), vT [72M,88M)  -> 88MB total
  unsigned short* xb     = (unsigned short*)(ws);
  unsigned short* ao     = (unsigned short*)(ws);             // alias: xb dead after GEMM1
  unsigned short* wqkvT  = (unsigned short*)(ws + (16u << 20));
  unsigned short* wprojT = (unsigned short*)(ws + (22u << 20));
  unsigned short* qkv    = (unsigned short*)(ws + (24u << 20));
  unsigned short* vT     = (unsigned short*)(ws + (72u << 20));

  cvt_f32_bf16_kernel<<<2048, 256, 0, stream>>>(x, xb, 8192 * 1024);
  transpose_cvt_kernel<<<dim3(3072 / 32, 1024 / 32), 256, 0, stream>>>(w_qkv, wqkvT, 1024, 3072);
  transpose_cvt_kernel<<<dim3(1024 / 32, 1024 / 32), 256, 0, stream>>>(w_proj, wprojT, 1024, 1024);

  gemm_bt_kernel<0><<<dim3(3072 / 128, 8192 / 128), 256, 0, stream>>>(
      xb, wqkvT, b_qkv, (void*)qkv, 8192, 3072, 1024);

  transpose_v_kernel<<<dim3(32, 64), 256, 0, stream>>>(qkv, vT);

  attn_kernel<<<dim3(32, 64), 256, 0, stream>>>(qkv, vT, ao);

  gemm_bt_kernel<1><<<dim3(1024 / 128, 8192 / 128), 256, 0, stream>>>(
      ao, wprojT, b_proj, (void*)out, 8192, 1024, 1024);
}

// Round 2
// 263.833 us; speedup vs baseline: 1.5052x; 1.5052x over previous
//
#include <hip/hip_runtime.h>
#include <hip/hip_bf16.h>

// B=4 T=2048 C=1024 H=16 hd=64, causal MHSA, f32 in/out, bf16 MFMA internally.
// Pipeline: cvt(x) / transpose-cvt(w) -> GEMM1 (qkv) -> transpose V -> flash attn -> GEMM2.

typedef float __attribute__((ext_vector_type(4))) f32x4;
typedef __bf16 __attribute__((ext_vector_type(8))) bf16x8;
typedef short __attribute__((ext_vector_type(8))) short8v;

__device__ __forceinline__ unsigned short f2bf(float f) {
  __hip_bfloat16 h = __float2bfloat16(f);
  return __builtin_bit_cast(unsigned short, h);
}

__device__ __forceinline__ void glds16(const void* g, void* l) {
  __builtin_amdgcn_global_load_lds((const __attribute__((address_space(1))) void*)g,
                                   (__attribute__((address_space(3))) void*)l, 16, 0, 0);
}

// ---------------- conversions ----------------
__global__ void cvt_f32_bf16_kernel(const float* __restrict__ in,
                                    unsigned short* __restrict__ out, int n) {
  int stride = gridDim.x * blockDim.x * 4;
  for (int i = (blockIdx.x * blockDim.x + threadIdx.x) * 4; i < n; i += stride) {
    float4 v = *(const float4*)(in + i);
    ushort4 o;
    o.x = f2bf(v.x); o.y = f2bf(v.y); o.z = f2bf(v.z); o.w = f2bf(v.w);
    *(ushort4*)(out + i) = o;
  }
}

// in: [K][N] f32 row-major -> out: [N][K] bf16 row-major
__global__ void transpose_cvt_kernel(const float* __restrict__ in,
                                     unsigned short* __restrict__ out, int K, int N) {
  __shared__ unsigned short tile[32][33];
  int tx = threadIdx.x & 31, ty = threadIdx.x >> 5;
  int n0 = blockIdx.x * 32, k0 = blockIdx.y * 32;
#pragma unroll
  for (int i = 0; i < 32; i += 8)
    tile[ty + i][tx] = f2bf(in[(size_t)(k0 + ty + i) * N + n0 + tx]);
  __syncthreads();
#pragma unroll
  for (int i = 0; i < 32; i += 8)
    out[(size_t)(n0 + ty + i) * K + k0 + tx] = tile[tx][ty + i];
}

// ---------------- GEMM: C[m][n] = sum_k A[m][k]*Bt[n][k] + bias[n] ----------------
// 128x128 tile, BK=32, 4 waves (2x2), 4x4 16x16x32 frags/wave. m97-style.
template <int OUT_F32>
__global__ __launch_bounds__(256) void gemm_bt_kernel(
    const unsigned short* __restrict__ A, const unsigned short* __restrict__ Bt,
    const float* __restrict__ bias, void* __restrict__ Cv, int M, int N, int K) {
  __shared__ unsigned short sA[128 * 32];
  __shared__ unsigned short sB[128 * 32];
  int tid = threadIdx.x;
  int lane = tid & 63, wid = tid >> 6;
  int g = lane >> 4, r16 = lane & 15;
  int m0 = blockIdx.y * 128, n0 = blockIdx.x * 128;
  int wm = wid >> 1, wn = wid & 1;
  f32x4 acc[4][4] = {};
  int srow = tid >> 2, scol = (tid & 3) * 8;
  const unsigned short* Ap0 = A + (size_t)(m0 + srow) * K + scol;
  const unsigned short* Ap1 = A + (size_t)(m0 + 64 + srow) * K + scol;
  const unsigned short* Bp0 = Bt + (size_t)(n0 + srow) * K + scol;
  const unsigned short* Bp1 = Bt + (size_t)(n0 + 64 + srow) * K + scol;
  unsigned short* la0 = sA + tid * 8;
  unsigned short* la1 = sA + 2048 + tid * 8;
  unsigned short* lb0 = sB + tid * 8;
  unsigned short* lb1 = sB + 2048 + tid * 8;
  for (int kt = 0; kt < K; kt += 32) {
    glds16(Ap0 + kt, la0);
    glds16(Ap1 + kt, la1);
    glds16(Bp0 + kt, lb0);
    glds16(Bp1 + kt, lb1);
    __syncthreads();
    bf16x8 af[4], bfr[4];
#pragma unroll
    for (int m = 0; m < 4; ++m)
      af[m] = *(const bf16x8*)&sA[(wm * 64 + m * 16 + r16) * 32 + g * 8];
#pragma unroll
    for (int n = 0; n < 4; ++n)
      bfr[n] = *(const bf16x8*)&sB[(wn * 64 + n * 16 + r16) * 32 + g * 8];
#pragma unroll
    for (int m = 0; m < 4; ++m)
#pragma unroll
      for (int n = 0; n < 4; ++n)
        acc[m][n] = __builtin_amdgcn_mfma_f32_16x16x32_bf16(af[m], bfr[n], acc[m][n], 0, 0, 0);
    __syncthreads();
  }
#pragma unroll
  for (int m = 0; m < 4; ++m)
#pragma unroll
    for (int n = 0; n < 4; ++n)
#pragma unroll
      for (int r = 0; r < 4; ++r) {
        int row = m0 + wm * 64 + m * 16 + g * 4 + r;
        int col = n0 + wn * 64 + n * 16 + r16;
        float v = acc[m][n][r] + bias[col];
        if (OUT_F32)
          ((float*)Cv)[(size_t)row * N + col] = v;
        else
          ((unsigned short*)Cv)[(size_t)row * N + col] = f2bf(v);
      }
}

// ---------------- V transpose: qkv[:, 2048+h*64+d] -> vT[(bh*64+d)][t] ----------------
__global__ void transpose_v_kernel(const unsigned short* __restrict__ qkv,
                                   unsigned short* __restrict__ vT) {
  __shared__ unsigned short tl[64][80];  // [d][t], padded
  int t0 = blockIdx.x * 64;
  int bh = blockIdx.y, b = bh >> 4, h = bh & 15;
  int tid = threadIdx.x;
  int row = tid >> 2, c0 = (tid & 3) * 16;  // row = t-local, c0 = d start
  const unsigned short* src =
      qkv + (size_t)(b * 2048 + t0 + row) * 3072 + 2048 + h * 64 + c0;
  short8v a0 = *(const short8v*)src;
  short8v a1 = *(const short8v*)(src + 8);
#pragma unroll
  for (int j = 0; j < 8; ++j) tl[c0 + j][row] = (unsigned short)a0[j];
#pragma unroll
  for (int j = 0; j < 8; ++j) tl[c0 + 8 + j][row] = (unsigned short)a1[j];
  __syncthreads();
  int d = tid >> 2, tc = (tid & 3) * 16;
  unsigned short* dst = vT + (size_t)(bh * 64 + d) * 2048 + t0 + tc;
  *(short8v*)dst = *(const short8v*)&tl[d][tc];
  *(short8v*)(dst + 8) = *(const short8v*)&tl[d][tc + 8];
}

// ---------------- flash attention ----------------
// 256 threads = 4 waves; QBLK=128 (32 q-rows/wave); KVBLK=64; double-buffered K/V
// (T3-min 2-phase: STAGE(next) -> compute(cur) -> syncthreads). Q in registers.
// Block handles q-tiles {p, 15-p} -> uniform 34 KV-iterations/block, grid 8x64.
// K/Vt staged via global_load_lds with pre-swizzled SOURCE (linear dest); reads
// XOR-deswizzle (oct ^= row&7) -> bank-conflict-free b128 reads.
__global__ __launch_bounds__(256) void attn_kernel(
    const unsigned short* __restrict__ qkv, const unsigned short* __restrict__ vT,
    unsigned short* __restrict__ ao) {
  __shared__ unsigned short sK[2][64 * 64];
  __shared__ unsigned short sV[2][64 * 64];   // V^T tile: [d][kv]
  __shared__ unsigned short sP[4][32 * 64];   // per-wave P, swizzled
  const int T = 2048, C3 = 3072;
  const float SCL = 0.18033688011112042f;     // 0.125 * log2(e)
  int pairI = blockIdx.x;                     // 0..7
  int bh = blockIdx.y, b = bh >> 4, h = bh & 15;
  int tid = threadIdx.x, lane = tid & 63, w = tid >> 6;
  int g = lane >> 4, r16 = lane & 15;

  // staging geometry: 2 chunks of 16B per thread per tensor
  int c0 = tid, c1 = 256 + tid;
  int row0 = c0 >> 3, oct0 = (c0 & 7) ^ (row0 & 7);
  int row1 = c1 >> 3, oct1 = (c1 & 7) ^ (row1 & 7);
  const unsigned short* Kb0 = qkv + (size_t)(b * T + row0) * C3 + 1024 + h * 64 + oct0 * 8;
  const unsigned short* Kb1 = qkv + (size_t)(b * T + row1) * C3 + 1024 + h * 64 + oct1 * 8;
  const unsigned short* Vb0 = vT + (size_t)(bh * 64 + row0) * 2048 + oct0 * 8;
  const unsigned short* Vb1 = vT + (size_t)(bh * 64 + row1) * 2048 + oct1 * 8;

  auto STAGE = [&](int buf, int kt) {
    int kv0 = kt * 64;
    glds16(Kb0 + (size_t)kv0 * C3, &sK[buf][c0 * 8]);
    glds16(Kb1 + (size_t)kv0 * C3, &sK[buf][c1 * 8]);
    glds16(Vb0 + kv0, &sV[buf][c0 * 8]);
    glds16(Vb1 + kv0, &sV[buf][c1 * 8]);
  };

#pragma unroll 1
  for (int half = 0; half < 2; ++half) {
    int qt = half ? (15 - pairI) : pairI;
    int qbase = qt * 128;
    int wq0 = qbase + w * 32;  // this wave's first q row (global)

    // Q fragments in registers: qf[m][kk]
    bf16x8 qf[2][2];
#pragma unroll
    for (int m = 0; m < 2; ++m)
#pragma unroll
      for (int kk = 0; kk < 2; ++kk)
        qf[m][kk] = *(const bf16x8*)(qkv + (size_t)(b * T + wq0 + m * 16 + r16) * C3 +
                                     h * 64 + kk * 32 + g * 8);

    f32x4 oacc[2][4] = {};
    float m_r[2][4], l_r[2][4];
#pragma unroll
    for (int m = 0; m < 2; ++m)
#pragma unroll
      for (int r = 0; r < 4; ++r) { m_r[m][r] = -1e30f; l_r[m][r] = 0.f; }

    int nkv = 2 * qt + 2;
    STAGE(0, 0);
    __syncthreads();
    int cur = 0;
#pragma unroll 1
    for (int kt = 0; kt < nkv; ++kt) {
      if (kt + 1 < nkv) STAGE(cur ^ 1, kt + 1);
      int kv0 = kt * 64;
      if (kv0 <= wq0 + 31) {  // wave-uniform: any valid (q,kv) in this tile?
        // ---- S = Q K^T ----
        f32x4 s[2][4] = {};
#pragma unroll
        for (int kk = 0; kk < 2; ++kk) {
          int octk = ((kk * 4 + g) ^ (r16 & 7)) * 8;
#pragma unroll
          for (int n = 0; n < 4; ++n) {
            bf16x8 kf = *(const bf16x8*)&sK[cur][(n * 16 + r16) * 64 + octk];
            s[0][n] = __builtin_amdgcn_mfma_f32_16x16x32_bf16(qf[0][kk], kf, s[0][n], 0, 0, 0);
            s[1][n] = __builtin_amdgcn_mfma_f32_16x16x32_bf16(qf[1][kk], kf, s[1][n], 0, 0, 0);
          }
        }
        // ---- online softmax (raw-s max; scale folded into exp2 fma) ----
        bool part = (kv0 + 63 > wq0);
        float rm[2][4];
#pragma unroll
        for (int m = 0; m < 2; ++m)
#pragma unroll
          for (int r = 0; r < 4; ++r) rm[m][r] = -1e30f;
#pragma unroll
        for (int m = 0; m < 2; ++m)
#pragma unroll
          for (int n = 0; n < 4; ++n)
#pragma unroll
            for (int r = 0; r < 4; ++r) {
              float v = s[m][n][r];
              if (part && (kv0 + n * 16 + r16) > (wq0 + m * 16 + g * 4 + r)) v = -1e30f;
              s[m][n][r] = v;
              rm[m][r] = fmaxf(rm[m][r], v);
            }
#pragma unroll
        for (int off = 1; off < 16; off <<= 1)
#pragma unroll
          for (int m = 0; m < 2; ++m)
#pragma unroll
            for (int r = 0; r < 4; ++r)
              rm[m][r] = fmaxf(rm[m][r], __shfl_xor(rm[m][r], off, 64));
        float alpha[2][4], nc[2][4], rs[2][4];
#pragma unroll
        for (int m = 0; m < 2; ++m)
#pragma unroll
          for (int r = 0; r < 4; ++r) {
            float mn = fmaxf(m_r[m][r], rm[m][r]);
            alpha[m][r] = exp2f((m_r[m][r] - mn) * SCL);
            m_r[m][r] = mn;
            nc[m][r] = mn * SCL;
            rs[m][r] = 0.f;
          }
#pragma unroll
        for (int m = 0; m < 2; ++m)
#pragma unroll
          for (int n = 0; n < 4; ++n)
#pragma unroll
            for (int r = 0; r < 4; ++r) {
              float p = exp2f(fmaf(s[m][n][r], SCL, -nc[m][r]));
              rs[m][r] += p;
              int ql = m * 16 + g * 4 + r, kv = n * 16 + r16;
              sP[w][ql * 64 + (((kv >> 3) ^ (ql & 7)) << 3) + (kv & 7)] = f2bf(p);
            }
#pragma unroll
        for (int off = 1; off < 16; off <<= 1)
#pragma unroll
          for (int m = 0; m < 2; ++m)
#pragma unroll
            for (int r = 0; r < 4; ++r)
              rs[m][r] += __shfl_xor(rs[m][r], off, 64);
#pragma unroll
        for (int m = 0; m < 2; ++m)
#pragma unroll
          for (int r = 0; r < 4; ++r) l_r[m][r] = l_r[m][r] * alpha[m][r] + rs[m][r];
#pragma unroll
        for (int m = 0; m < 2; ++m)
#pragma unroll
          for (int n2 = 0; n2 < 4; ++n2)
#pragma unroll
            for (int r = 0; r < 4; ++r) oacc[m][n2][r] *= alpha[m][r];
        // ---- O += P V ----
#pragma unroll
        for (int kk = 0; kk < 2; ++kk) {
          int octk = ((kk * 4 + g) ^ (r16 & 7)) * 8;
          bf16x8 pf0 = *(const bf16x8*)&sP[w][r16 * 64 + octk];
          bf16x8 pf1 = *(const bf16x8*)&sP[w][(16 + r16) * 64 + octk];
#pragma unroll
          for (int n2 = 0; n2 < 4; ++n2) {
            bf16x8 vf = *(const bf16x8*)&sV[cur][(n2 * 16 + r16) * 64 + octk];
            oacc[0][n2] = __builtin_amdgcn_mfma_f32_16x16x32_bf16(pf0, vf, oacc[0][n2], 0, 0, 0);
            oacc[1][n2] = __builtin_amdgcn_mfma_f32_16x16x32_bf16(pf1, vf, oacc[1][n2], 0, 0, 0);
          }
        }
      }
      __syncthreads();  // drains vmcnt for next tile + protects buffer swap
      cur ^= 1;
    }

    // ---- store O / l ----
#pragma unroll
    for (int m = 0; m < 2; ++m)
#pragma unroll
      for (int r = 0; r < 4; ++r) {
        float inv = 1.f / l_r[m][r];
        int q = wq0 + m * 16 + g * 4 + r;
#pragma unroll
        for (int n2 = 0; n2 < 4; ++n2) {
          int d = h * 64 + n2 * 16 + r16;
          ao[(size_t)(b * T + q) * 1024 + d] = f2bf(oacc[m][n2][r] * inv);
        }
      }
  }
}

// ---------------- launch ----------------
extern "C" void kernel_launch(void* const* d_in, const int* in_sizes, int n_in,
                              void* d_out, int out_size, void* d_ws, size_t ws_size,
                              hipStream_t stream) {
  const float* x      = (const float*)d_in[0];
  const float* w_qkv  = (const float*)d_in[1];
  const float* b_qkv  = (const float*)d_in[2];
  const float* w_proj = (const float*)d_in[3];
  const float* b_proj = (const float*)d_in[4];
  float* out = (float*)d_out;

  char* ws = (char*)d_ws;
  // layout (bytes): xb/ao alias [0,16M), wqkvT [16M,22M), wprojT [22M,24M),
  // qkv [24M,72M), vT [72M,88M)
  unsigned short* xb     = (unsigned short*)(ws);
  unsigned short* ao     = (unsigned short*)(ws);             // alias: xb dead after GEMM1
  unsigned short* wqkvT  = (unsigned short*)(ws + (16u << 20));
  unsigned short* wprojT = (unsigned short*)(ws + (22u << 20));
  unsigned short* qkv    = (unsigned short*)(ws + (24u << 20));
  unsigned short* vT     = (unsigned short*)(ws + (72u << 20));

  cvt_f32_bf16_kernel<<<2048, 256, 0, stream>>>(x, xb, 8192 * 1024);
  transpose_cvt_kernel<<<dim3(3072 / 32, 1024 / 32), 256, 0, stream>>>(w_qkv, wqkvT, 1024, 3072);
  transpose_cvt_kernel<<<dim3(1024 / 32, 1024 / 32), 256, 0, stream>>>(w_proj, wprojT, 1024, 1024);

  gemm_bt_kernel<0><<<dim3(3072 / 128, 8192 / 128), 256, 0, stream>>>(
      xb, wqkvT, b_qkv, (void*)qkv, 8192, 3072, 1024);

  transpose_v_kernel<<<dim3(32, 64), 256, 0, stream>>>(qkv, vT);

  attn_kernel<<<dim3(8, 64), 256, 0, stream>>>(qkv, vT, ao);

  gemm_bt_kernel<1><<<dim3(1024 / 128, 8192 / 128), 256, 0, stream>>>(
      ao, wprojT, b_proj, (void*)out, 8192, 1024, 1024);
}